// Round 3
// baseline (244.747 us; speedup 1.0000x reference)
//
#include <hip/hip_runtime.h>
#include <hip/hip_cooperative_groups.h>

namespace cg = cooperative_groups;

// Problem constants (from reference)
constexpr int kB   = 16384;   // batch
constexpr int kNeg = 10;      // negatives per example
constexpr int kE   = 128;     // embedding dim

// Cooperative config: 1024 blocks x 256 threads, __launch_bounds__(256,4)
// -> 4 blocks/CU x 256 CUs = 1024 co-resident blocks (guaranteed fit).
// Each wave: 2 examples per pass (32 lanes each), 2 passes -> 16 ex/block.
constexpr int kCoopBlocks = 1024;
constexpr int kPasses     = kB / (kCoopBlocks * 8);   // 2

__device__ __forceinline__ float log_sigmoid(float x) {
    // numerically stable: min(x,0) - log1p(exp(-|x|))
    return fminf(x, 0.0f) - log1pf(expf(-fabsf(x)));
}

__device__ __forceinline__ float dot4(float4 a, float4 b) {
    return a.x * b.x + a.y * b.y + a.z * b.z + a.w * b.w;
}

// Per-pass work for one example pair (round-0 proven body):
// 32 lanes per example; one float4 per lane covers the E=128 row exactly;
// all 12 row gathers issued back-to-back for max memory-level parallelism.
// Returns the wave-wide 22-term sum (both halves) broadcast to all lanes.
__device__ __forceinline__ float wave_pass(
    int b, int l32, int half,
    const int*   __restrict__ input_word,
    const int*   __restrict__ context_word,
    const int*   __restrict__ noise_words,
    const float* __restrict__ W_in,
    const float* __restrict__ W_ctx)
{
    const int iw = input_word[b];
    const int cw = context_word[b];
    int nw[kNeg];
    #pragma unroll
    for (int k = 0; k < kNeg; ++k)
        nw[k] = noise_words[b * kNeg + k];

    const float4 c = ((const float4*)(W_in  + (size_t)iw * kE))[l32];
    const float4 x = ((const float4*)(W_ctx + (size_t)cw * kE))[l32];
    float4 nv[kNeg];
    #pragma unroll
    for (int k = 0; k < kNeg; ++k)
        nv[k] = ((const float4*)(W_ctx + (size_t)nw[k] * kE))[l32];

    float pos = dot4(c, x);
    float negp[kNeg];
    #pragma unroll
    for (int k = 0; k < kNeg; ++k)
        negp[k] = dot4(c, nv[k]);

    // 5-step butterfly within each 32-lane half (xor masks < 32 stay in-half).
    #pragma unroll
    for (int off = 16; off > 0; off >>= 1) {
        pos += __shfl_xor(pos, off);
        #pragma unroll
        for (int k = 0; k < kNeg; ++k)
            negp[k] += __shfl_xor(negp[k], off);
    }

    // Distribute the 11 log_sigmoid evaluations across lanes 0..10 of the half.
    float v = pos;
    #pragma unroll
    for (int k = 0; k < kNeg; ++k)
        v = (l32 == k + 1) ? -negp[k] : v;
    float s = (l32 < 1 + kNeg) ? log_sigmoid(v) : 0.0f;

    // Sum the 11 terms within the half, then across halves.
    #pragma unroll
    for (int off = 16; off > 0; off >>= 1)
        s += __shfl_xor(s, off);
    s += __shfl_xor(s, 32);
    return s;   // every lane holds the wave's 2-example total
}

// --- fused cooperative kernel: loss + grid-wide reduction in ONE dispatch ---
__global__ __launch_bounds__(256, 4) void w2v_fused(
    const int*   __restrict__ input_word,
    const int*   __restrict__ context_word,
    const int*   __restrict__ noise_words,
    const float* __restrict__ W_in,
    const float* __restrict__ W_ctx,
    float*       __restrict__ partials,
    float*       __restrict__ out)
{
    const int tid  = threadIdx.x;
    const int wave = tid >> 6;
    const int lane = tid & 63;
    const int half = lane >> 5;
    const int l32  = lane & 31;

    float wsum = 0.0f;
    #pragma unroll
    for (int pass = 0; pass < kPasses; ++pass) {
        const int b = ((pass * kCoopBlocks + blockIdx.x) * 4 + wave) * 2 + half;
        wsum += wave_pass(b, l32, half,
                          input_word, context_word, noise_words, W_in, W_ctx);
    }

    __shared__ float smem[4];
    if (lane == 0) smem[wave] = wsum;
    __syncthreads();
    if (tid == 0)
        partials[blockIdx.x] = smem[0] + smem[1] + smem[2] + smem[3];

    cg::this_grid().sync();

    // Deterministic final reduction by block 0.
    if (blockIdx.x == 0) {
        float acc = 0.0f;
        for (int i = tid; i < kCoopBlocks; i += 256)
            acc += partials[i];
        #pragma unroll
        for (int off = 32; off > 0; off >>= 1)
            acc += __shfl_xor(acc, off);
        __shared__ float sm2[4];
        if (lane == 0) sm2[wave] = acc;
        __syncthreads();
        if (tid == 0)
            out[0] = -(sm2[0] + sm2[1] + sm2[2] + sm2[3]) / (float)kB;
    }
}

// --- fallback pair (used only if cooperative launch is unavailable) ---------
constexpr int kFbBlocks = kB / 8;   // 2048: 4 waves x 2 examples, one pass

__global__ __launch_bounds__(256, 4) void w2v_loss_kernel(
    const int*   __restrict__ input_word,
    const int*   __restrict__ context_word,
    const int*   __restrict__ noise_words,
    const float* __restrict__ W_in,
    const float* __restrict__ W_ctx,
    float*       __restrict__ partials)
{
    const int tid  = threadIdx.x;
    const int wave = tid >> 6;
    const int lane = tid & 63;
    const int half = lane >> 5;
    const int l32  = lane & 31;
    const int b = (blockIdx.x * 4 + wave) * 2 + half;

    const float s = wave_pass(b, l32, half,
                              input_word, context_word, noise_words, W_in, W_ctx);

    __shared__ float smem[4];
    if (lane == 0) smem[wave] = s;
    __syncthreads();
    if (tid == 0)
        partials[blockIdx.x] = smem[0] + smem[1] + smem[2] + smem[3];
}

__global__ __launch_bounds__(256) void w2v_reduce_kernel(
    const float* __restrict__ partials,
    float*       __restrict__ out)
{
    float acc = 0.0f;
    for (int i = threadIdx.x; i < kFbBlocks; i += 256)
        acc += partials[i];
    #pragma unroll
    for (int off = 32; off > 0; off >>= 1)
        acc += __shfl_xor(acc, off);
    __shared__ float smem[4];
    const int lane = threadIdx.x & 63;
    const int wave = threadIdx.x >> 6;
    if (lane == 0) smem[wave] = acc;
    __syncthreads();
    if (threadIdx.x == 0)
        out[0] = -(smem[0] + smem[1] + smem[2] + smem[3]) / (float)kB;
}

extern "C" void kernel_launch(void* const* d_in, const int* in_sizes, int n_in,
                              void* d_out, int out_size, void* d_ws, size_t ws_size,
                              hipStream_t stream) {
    const int*   input_word   = (const int*)d_in[0];
    const int*   context_word = (const int*)d_in[1];
    const int*   noise_words  = (const int*)d_in[2];
    const float* W_in         = (const float*)d_in[3];
    const float* W_ctx        = (const float*)d_in[4];
    float*       out          = (float*)d_out;
    float*       partials     = (float*)d_ws;   // kCoopBlocks floats (4 KiB)

    void* args[] = {
        (void*)&input_word, (void*)&context_word, (void*)&noise_words,
        (void*)&W_in, (void*)&W_ctx, (void*)&partials, (void*)&out
    };
    hipError_t err = hipLaunchCooperativeKernel(
        (const void*)w2v_fused, dim3(kCoopBlocks), dim3(256), args, 0, stream);

    if (err != hipSuccess) {
        // Fallback: classic two-kernel path (proven correct & fast).
        w2v_loss_kernel<<<kFbBlocks, 256, 0, stream>>>(
            input_word, context_word, noise_words, W_in, W_ctx, partials);
        w2v_reduce_kernel<<<1, 256, 0, stream>>>(partials, out);
    }
}